// Round 1
// baseline (284.957 us; speedup 1.0000x reference)
//
#include <hip/hip_runtime.h>
#include <cstdint>

#define EPSF 1e-5f

// ============================== prep ==============================
// Packs sign bits of w2 and w_fc, computes BN3 constants, transposes w_last.
__global__ __launch_bounds__(256) void prep_kernel(
    const float* __restrict__ w2, const float* __restrict__ wfc,
    const float* __restrict__ g3, const float* __restrict__ be3,
    const float* __restrict__ m3, const float* __restrict__ v3,
    const float* __restrict__ wlast,
    uint32_t* __restrict__ w2bits, uint32_t* __restrict__ wfcb,
    float* __restrict__ inv3p, float* __restrict__ sh3p, float* __restrict__ wlt)
{
    int id = blockIdx.x * 256 + threadIdx.x;
    if (id < 288) {                       // w2 sign pack: [co][ky*3+kx], bit ci
        int co = id / 9, r = id % 9;
        uint32_t b = 0;
        for (int ci = 0; ci < 32; ci++)
            b |= (uint32_t)(w2[(co * 32 + ci) * 9 + r] < 0.f) << ci;
        w2bits[id] = b;
        return;
    }
    id -= 288;
    if (id < 36 * 576) {                  // w_fc sign pack: [w][j] (j padded to 576)
        int w = id / 576, j = id % 576;
        uint32_t b = 0;
        if (j < 516) {
            const float* row = wfc + j * 1152 + w * 32;
            for (int t = 0; t < 32; t++)
                b |= (uint32_t)(row[t] < 0.f) << t;
        }
        wfcb[id] = b;
        return;
    }
    id -= 36 * 576;
    if (id < 576) {                       // BN3 constants (pad -> 0 so t=0)
        float iv = 0.f, sh = 0.f;
        if (id < 516) {
            iv = g3[id] / sqrtf(__fadd_rn(v3[id], EPSF));
            sh = __fsub_rn(be3[id], __fmul_rn(m3[id], iv));
        }
        inv3p[id] = iv; sh3p[id] = sh;
        return;
    }
    id -= 576;
    if (id < 5760) {                      // w_last transpose: wlt[j*10+k]
        int j = id / 10, k = id % 10;
        wlt[id] = (j < 516) ? wlast[k * 516 + j] : 0.f;
    }
}

// ================== conv1 fp64 sign recheck (rare) ==================
__device__ __noinline__ bool recheck_sign(const float* xim, const float* wl,
                                          int y, int p, int co,
                                          float b0c, float ivc, float shc)
{
    double ad = 0.0;
    for (int ci = 0; ci < 8; ci++)
        for (int ky = 0; ky < 3; ky++)
            for (int kx = 0; kx < 3; kx++)
                ad = fma((double)xim[ci * 256 + (y + ky) * 16 + p + kx],
                         (double)wl[(((ci * 3 + ky) * 3) + kx) * 32 + co], ad);
    double yd = (ad + (double)b0c) * (double)ivc + (double)shc;
    return yd < 0.0;
}

// ============================== convA ==============================
// conv1 + bias + BN1 + sign -> bitpack over 32 channels.
// thread = (image, output row y, channel group cg of 4). 56 accumulators.
__global__ __launch_bounds__(256) void convA(
    const float* __restrict__ x, const float* __restrict__ w0,
    const float* __restrict__ b0, const float* __restrict__ g1,
    const float* __restrict__ be1, const float* __restrict__ m1,
    const float* __restrict__ v1, uint32_t* __restrict__ s1bits)
{
    __shared__ float wl[2304];            // [ci][ky][kx][co]
    __shared__ float bb[32], iv[32], sh[32];
    __shared__ uint32_t pack[32][14];     // 32 (img,y) rows per block

    const int t = threadIdx.x;
    for (int i = t; i < 2304; i += 256) {
        int co = i & 31, q = i >> 5;
        int kx = q % 3, ky = (q / 3) % 3, ci = q / 9;
        wl[i] = w0[co * 72 + ci * 9 + ky * 3 + kx];
    }
    if (t < 32) {
        float ivv = g1[t] / sqrtf(__fadd_rn(v1[t], EPSF));
        iv[t] = ivv;
        sh[t] = __fsub_rn(be1[t], __fmul_rn(m1[t], ivv));
        bb[t] = b0[t];
    }
    for (int i = t; i < 448; i += 256) ((uint32_t*)pack)[i] = 0u;
    __syncthreads();

    const int tg  = blockIdx.x * 256 + t;
    const int img = tg / 112;
    const int r   = tg - img * 112;
    const int y   = r >> 3;               // output row 0..13
    const int cg  = r & 7;                // channel group (co = 4cg..4cg+3)
    const float* xim = x + img * 2048;

    float acc[4][14];
    #pragma unroll
    for (int c = 0; c < 4; c++)
        #pragma unroll
        for (int p = 0; p < 14; p++) acc[c][p] = 0.f;

    for (int ci = 0; ci < 8; ci++) {
        const float* base = xim + ci * 256 + y * 16;
        #pragma unroll
        for (int ky = 0; ky < 3; ky++) {
            const float4* rp = (const float4*)(base + ky * 16);
            float4 r0 = rp[0], r1 = rp[1], r2 = rp[2], r3 = rp[3];
            float px[16] = { r0.x, r0.y, r0.z, r0.w, r1.x, r1.y, r1.z, r1.w,
                             r2.x, r2.y, r2.z, r2.w, r3.x, r3.y, r3.z, r3.w };
            #pragma unroll
            for (int kx = 0; kx < 3; kx++) {
                float4 wv = *(const float4*)&wl[(((ci * 3 + ky) * 3) + kx) * 32 + 4 * cg];
                #pragma unroll
                for (int p = 0; p < 14; p++) {
                    acc[0][p] = fmaf(px[p + kx], wv.x, acc[0][p]);
                    acc[1][p] = fmaf(px[p + kx], wv.y, acc[1][p]);
                    acc[2][p] = fmaf(px[p + kx], wv.z, acc[2][p]);
                    acc[3][p] = fmaf(px[p + kx], wv.w, acc[3][p]);
                }
            }
        }
    }

    float b0c[4], ivc[4], shc[4];
    #pragma unroll
    for (int c = 0; c < 4; c++) {
        b0c[c] = bb[4 * cg + c]; ivc[c] = iv[4 * cg + c]; shc[c] = sh[4 * cg + c];
    }

    const int rloc = t >> 3;
    const uint32_t shift = (uint32_t)(cg * 4);
    unsigned long long prov = 0ull, need = 0ull;   // bit idx = p*4 + c

    #pragma unroll
    for (int p = 0; p < 14; p++) {
        uint32_t nib = 0;
        #pragma unroll
        for (int c = 0; c < 4; c++) {
            float h  = __fadd_rn(acc[c][p], b0c[c]);
            float yv = __fadd_rn(__fmul_rn(h, ivc[c]), shc[c]);
            bool bit = (yv < 0.f);
            int idx = p * 4 + c;
            prov |= (unsigned long long)bit << idx;
            if (fabsf(yv) < 3e-4f) need |= 1ull << idx;
            nib |= (uint32_t)bit << c;
        }
        atomicOr(&pack[rloc][p], nib << shift);
    }
    // rare fp64 recheck of borderline signs; fix bits with atomicXor
    while (need) {
        int idx = __ffsll(need) - 1;
        need &= need - 1ull;
        int p = idx >> 2, c = idx & 3;
        bool nb = recheck_sign(xim, wl, y, p, 4 * cg + c, b0c[c], ivc[c], shc[c]);
        if (nb != (bool)((prov >> idx) & 1ull))
            atomicXor(&pack[rloc][p], 1u << (shift + c));
    }
    __syncthreads();

    for (int i = t; i < 448; i += 256) {
        int rg  = blockIdx.x * 32 + (i / 14);
        int p   = i % 14;
        int im2 = rg / 14, yy = rg - im2 * 14;
        s1bits[im2 * 196 + yy * 14 + p] = ((const uint32_t*)pack)[i];
    }
}

// ============================== convB ==============================
// binary conv2 + BN2 + hardtanh + maxpool + sign -> 36 u32 words per image.
// pooled sign == sign(max(o)*inv2 + sh2) by monotonicity of BN/clip/max.
__global__ __launch_bounds__(256) void convB(
    const uint32_t* __restrict__ s1bits, const uint32_t* __restrict__ w2bits,
    const float* __restrict__ g2, const float* __restrict__ be2,
    const float* __restrict__ m2, const float* __restrict__ v2,
    uint32_t* __restrict__ fcin)
{
    __shared__ uint32_t s1l[4][196];
    __shared__ uint32_t w2l[288];
    __shared__ float iv[32], sh[32];
    const int t = threadIdx.x, wid = t >> 6, lane = t & 63;

    for (int i = t; i < 288; i += 256) w2l[i] = w2bits[i];
    if (t < 32) {
        float v = g2[t] / sqrtf(__fadd_rn(v2[t], EPSF));
        iv[t] = v;
        sh[t] = __fsub_rn(be2[t], __fmul_rn(m2[t], v));
    }
    const int img = blockIdx.x * 4 + wid;
    for (int i = lane; i < 196; i += 64) s1l[wid][i] = s1bits[img * 196 + i];
    __syncthreads();

    uint32_t* outp = fcin + img * 36;
    const uint32_t* s1w = s1l[wid];

    for (int i = 0; i < 18; i++) {
        int k = i * 64 + lane;            // flattened feature 36c + 6y2 + x2
        int c = k / 36, rem = k - c * 36;
        int y2 = rem / 6, x2 = rem - y2 * 6;
        const uint32_t* wc = &w2l[c * 9];
        uint32_t w00 = wc[0], w01 = wc[1], w02 = wc[2],
                 w10 = wc[3], w11 = wc[4], w12 = wc[5],
                 w20 = wc[6], w21 = wc[7], w22 = wc[8];
        int mx = -10000;
        #pragma unroll
        for (int dy = 0; dy < 2; dy++)
            #pragma unroll
            for (int dx = 0; dx < 2; dx++) {
                const uint32_t* rb = &s1w[(2 * y2 + dy) * 14 + 2 * x2 + dx];
                int p = __popc(rb[0]  ^ w00) + __popc(rb[1]  ^ w01) + __popc(rb[2]  ^ w02)
                      + __popc(rb[14] ^ w10) + __popc(rb[15] ^ w11) + __popc(rb[16] ^ w12)
                      + __popc(rb[28] ^ w20) + __popc(rb[29] ^ w21) + __popc(rb[30] ^ w22);
                int o = 288 - 2 * p;
                mx = max(mx, o);
            }
        float yv = __fadd_rn(__fmul_rn((float)mx, iv[c]), sh[c]);
        unsigned long long mb = __ballot(yv < 0.f);
        if (lane == 0)      outp[2 * i]     = (uint32_t)mb;
        else if (lane == 1) outp[2 * i + 1] = (uint32_t)(mb >> 32);
    }
}

// ============================== fcC ==============================
// binary FC (popcount) + BN3 + hardtanh + final 516x10 linear, fused.
// wave handles 4 batches; lane handles features j = lane + 64q, q=0..8 (576 padded).
__global__ __launch_bounds__(256) void fcC(
    const uint32_t* __restrict__ fcin, const uint32_t* __restrict__ wfcb,
    const float* __restrict__ inv3p, const float* __restrict__ sh3p,
    const float* __restrict__ wlt, const float* __restrict__ blast,
    float* __restrict__ out)
{
    const int t = threadIdx.x, wid = t >> 6, lane = t & 63;
    const int grp = blockIdx.x * 4 + wid;
    const int b0i = grp * 4;
    const uint32_t* in0 = fcin + b0i * 36;

    float oa[4][10];
    #pragma unroll
    for (int b = 0; b < 4; b++)
        #pragma unroll
        for (int k = 0; k < 10; k++) oa[b][k] = 0.f;

    for (int q = 0; q < 9; q++) {
        int j = lane + 64 * q;
        int p0 = 0, p1 = 0, p2 = 0, p3 = 0;
        const uint32_t* wf = wfcb + j;
        #pragma unroll
        for (int w = 0; w < 36; w++) {
            uint32_t f = wf[w * 576];
            p0 += __popc(in0[w]       ^ f);
            p1 += __popc(in0[36 + w]  ^ f);
            p2 += __popc(in0[72 + w]  ^ f);
            p3 += __popc(in0[108 + w] ^ f);
        }
        float ivv = inv3p[j], shv = sh3p[j];
        float t0 = fminf(1.f, fmaxf(-1.f, __fadd_rn(__fmul_rn((float)(1152 - 2 * p0), ivv), shv)));
        float t1 = fminf(1.f, fmaxf(-1.f, __fadd_rn(__fmul_rn((float)(1152 - 2 * p1), ivv), shv)));
        float t2 = fminf(1.f, fmaxf(-1.f, __fadd_rn(__fmul_rn((float)(1152 - 2 * p2), ivv), shv)));
        float t3 = fminf(1.f, fmaxf(-1.f, __fadd_rn(__fmul_rn((float)(1152 - 2 * p3), ivv), shv)));
        const float* wrow = wlt + j * 10;
        #pragma unroll
        for (int k = 0; k < 10; k++) {
            float wv = wrow[k];
            oa[0][k] = fmaf(t0, wv, oa[0][k]);
            oa[1][k] = fmaf(t1, wv, oa[1][k]);
            oa[2][k] = fmaf(t2, wv, oa[2][k]);
            oa[3][k] = fmaf(t3, wv, oa[3][k]);
        }
    }

    #pragma unroll
    for (int m = 1; m < 64; m <<= 1)
        #pragma unroll
        for (int b = 0; b < 4; b++)
            #pragma unroll
            for (int k = 0; k < 10; k++)
                oa[b][k] += __shfl_xor(oa[b][k], m, 64);

    if (lane == 0) {
        for (int b = 0; b < 4; b++)
            for (int k = 0; k < 10; k++)
                out[(b0i + b) * 10 + k] = oa[b][k] + blast[k];
    }
}

// ============================== launch ==============================
extern "C" void kernel_launch(void* const* d_in, const int* in_sizes, int n_in,
                              void* d_out, int out_size, void* d_ws, size_t ws_size,
                              hipStream_t stream)
{
    (void)in_sizes; (void)n_in; (void)out_size; (void)ws_size;
    const float* x     = (const float*)d_in[0];
    const float* w0    = (const float*)d_in[1];
    const float* b0    = (const float*)d_in[2];
    const float* g1    = (const float*)d_in[3];
    const float* be1   = (const float*)d_in[4];
    const float* m1    = (const float*)d_in[5];
    const float* v1    = (const float*)d_in[6];
    const float* w2    = (const float*)d_in[7];
    const float* g2    = (const float*)d_in[8];
    const float* be2   = (const float*)d_in[9];
    const float* m2    = (const float*)d_in[10];
    const float* v2    = (const float*)d_in[11];
    const float* wfc   = (const float*)d_in[12];
    const float* g3    = (const float*)d_in[13];
    const float* be3   = (const float*)d_in[14];
    const float* m3    = (const float*)d_in[15];
    const float* v3    = (const float*)d_in[16];
    const float* wlast = (const float*)d_in[17];
    const float* blast = (const float*)d_in[18];

    char* ws = (char*)d_ws;
    uint32_t* s1bits = (uint32_t*)(ws);                 // 8192*196*4 = 6,422,528 B
    uint32_t* fcin   = (uint32_t*)(ws + 6422528);       // 8192*36*4  = 1,179,648 B
    uint32_t* w2bits = (uint32_t*)(ws + 7602176);       // 288*4
    uint32_t* wfcb   = (uint32_t*)(ws + 7603328);       // 36*576*4 = 82,944 B
    float*    inv3p  = (float*)(ws + 7686272);          // 576*4
    float*    sh3p   = (float*)(ws + 7688576);          // 576*4
    float*    wlt    = (float*)(ws + 7690880);          // 576*10*4 = 23,040 B

    prep_kernel<<<107, 256, 0, stream>>>(w2, wfc, g3, be3, m3, v3, wlast,
                                         w2bits, wfcb, inv3p, sh3p, wlt);
    convA<<<3584, 256, 0, stream>>>(x, w0, b0, g1, be1, m1, v1, s1bits);
    convB<<<2048, 256, 0, stream>>>(s1bits, w2bits, g2, be2, m2, v2, fcin);
    fcC<<<512, 256, 0, stream>>>(fcin, wfcb, inv3p, sh3p, wlt, blast, (float*)d_out);
}

// Round 2
// 282.974 us; speedup vs baseline: 1.0070x; 1.0070x over previous
//
#include <hip/hip_runtime.h>
#include <cstdint>

#define EPSF 1e-5f

// ============================== prep ==============================
// Packs sign bits of w2 and w_fc, computes BN3 constants, transposes w_last.
// wlt layout: [k][j] (k=0..9, j padded to 576) for coalesced fcC reads.
__global__ __launch_bounds__(256) void prep_kernel(
    const float* __restrict__ w2, const float* __restrict__ wfc,
    const float* __restrict__ g3, const float* __restrict__ be3,
    const float* __restrict__ m3, const float* __restrict__ v3,
    const float* __restrict__ wlast,
    uint32_t* __restrict__ w2bits, uint32_t* __restrict__ wfcb,
    float* __restrict__ inv3p, float* __restrict__ sh3p, float* __restrict__ wlt)
{
    int id = blockIdx.x * 256 + threadIdx.x;
    if (id < 288) {                       // w2 sign pack: [co][ky*3+kx], bit ci
        int co = id / 9, r = id % 9;
        uint32_t b = 0;
        for (int ci = 0; ci < 32; ci++)
            b |= (uint32_t)(w2[(co * 32 + ci) * 9 + r] < 0.f) << ci;
        w2bits[id] = b;
        return;
    }
    id -= 288;
    if (id < 36 * 576) {                  // w_fc sign pack: [w][j] (j padded to 576)
        int w = id / 576, j = id % 576;
        uint32_t b = 0;
        if (j < 516) {
            const float* row = wfc + j * 1152 + w * 32;
            for (int t = 0; t < 32; t++)
                b |= (uint32_t)(row[t] < 0.f) << t;
        }
        wfcb[id] = b;
        return;
    }
    id -= 36 * 576;
    if (id < 576) {                       // BN3 constants (pad -> 0 so t=0)
        float iv = 0.f, sh = 0.f;
        if (id < 516) {
            iv = g3[id] / sqrtf(__fadd_rn(v3[id], EPSF));
            sh = __fsub_rn(be3[id], __fmul_rn(m3[id], iv));
        }
        inv3p[id] = iv; sh3p[id] = sh;
        return;
    }
    id -= 576;
    if (id < 5760) {                      // w_last transpose: wlt[k*576 + j]
        int k = id / 576, j = id % 576;
        wlt[id] = (j < 516) ? wlast[k * 516 + j] : 0.f;
    }
}

// ================== conv1 fp64 sign recheck (rare) ==================
__device__ __noinline__ bool recheck_sign(const float* xim, const float* wl,
                                          int y, int p, int co,
                                          float b0c, float ivc, float shc)
{
    double ad = 0.0;
    for (int ci = 0; ci < 8; ci++)
        for (int ky = 0; ky < 3; ky++)
            for (int kx = 0; kx < 3; kx++)
                ad = fma((double)xim[ci * 256 + (y + ky) * 16 + p + kx],
                         (double)wl[(((ci * 3 + ky) * 3) + kx) * 32 + co], ad);
    double yd = (ad + (double)b0c) * (double)ivc + (double)shc;
    return yd < 0.0;
}

// ============================== convA ==============================
// conv1 + bias + BN1 + sign -> bitpack over 32 channels.
// thread = (image, output row y, channel group cg of 4). 56 accumulators.
// __launch_bounds__(256, 4): cap occupancy at 4 blocks/CU so the register
// allocator gets ~128 VGPRs — the 56 accumulators must live in arch VGPRs,
// not ping-pong through AGPR spill (which tripled VALU issue at 64 VGPRs).
__global__ __launch_bounds__(256, 4) void convA(
    const float* __restrict__ x, const float* __restrict__ w0,
    const float* __restrict__ b0, const float* __restrict__ g1,
    const float* __restrict__ be1, const float* __restrict__ m1,
    const float* __restrict__ v1, uint32_t* __restrict__ s1bits)
{
    __shared__ float wl[2304];            // [ci][ky][kx][co]
    __shared__ float bb[32], iv[32], sh[32];
    __shared__ uint32_t pack[32][14];     // 32 (img,y) rows per block

    const int t = threadIdx.x;
    for (int i = t; i < 2304; i += 256) {
        int co = i & 31, q = i >> 5;
        int kx = q % 3, ky = (q / 3) % 3, ci = q / 9;
        wl[i] = w0[co * 72 + ci * 9 + ky * 3 + kx];
    }
    if (t < 32) {
        float ivv = g1[t] / sqrtf(__fadd_rn(v1[t], EPSF));
        iv[t] = ivv;
        sh[t] = __fsub_rn(be1[t], __fmul_rn(m1[t], ivv));
        bb[t] = b0[t];
    }
    for (int i = t; i < 448; i += 256) ((uint32_t*)pack)[i] = 0u;
    __syncthreads();

    const int tg  = blockIdx.x * 256 + t;
    const int img = tg / 112;
    const int r   = tg - img * 112;
    const int y   = r >> 3;               // output row 0..13
    const int cg  = r & 7;                // channel group (co = 4cg..4cg+3)
    const float* xim = x + img * 2048;

    float acc[4][14];
    #pragma unroll
    for (int c = 0; c < 4; c++)
        #pragma unroll
        for (int p = 0; p < 14; p++) acc[c][p] = 0.f;

    for (int ci = 0; ci < 8; ci++) {
        const float* base = xim + ci * 256 + y * 16;
        #pragma unroll
        for (int ky = 0; ky < 3; ky++) {
            const float4* rp = (const float4*)(base + ky * 16);
            float4 r0 = rp[0], r1 = rp[1], r2 = rp[2], r3 = rp[3];
            float px[16] = { r0.x, r0.y, r0.z, r0.w, r1.x, r1.y, r1.z, r1.w,
                             r2.x, r2.y, r2.z, r2.w, r3.x, r3.y, r3.z, r3.w };
            #pragma unroll
            for (int kx = 0; kx < 3; kx++) {
                float4 wv = *(const float4*)&wl[(((ci * 3 + ky) * 3) + kx) * 32 + 4 * cg];
                #pragma unroll
                for (int p = 0; p < 14; p++) {
                    acc[0][p] = fmaf(px[p + kx], wv.x, acc[0][p]);
                    acc[1][p] = fmaf(px[p + kx], wv.y, acc[1][p]);
                    acc[2][p] = fmaf(px[p + kx], wv.z, acc[2][p]);
                    acc[3][p] = fmaf(px[p + kx], wv.w, acc[3][p]);
                }
            }
        }
    }

    float b0c[4], ivc[4], shc[4];
    #pragma unroll
    for (int c = 0; c < 4; c++) {
        b0c[c] = bb[4 * cg + c]; ivc[c] = iv[4 * cg + c]; shc[c] = sh[4 * cg + c];
    }

    const int rloc = t >> 3;
    const uint32_t shift = (uint32_t)(cg * 4);
    unsigned long long prov = 0ull, need = 0ull;   // bit idx = p*4 + c

    #pragma unroll
    for (int p = 0; p < 14; p++) {
        uint32_t nib = 0;
        #pragma unroll
        for (int c = 0; c < 4; c++) {
            float h  = __fadd_rn(acc[c][p], b0c[c]);
            float yv = __fadd_rn(__fmul_rn(h, ivc[c]), shc[c]);
            bool bit = (yv < 0.f);
            int idx = p * 4 + c;
            prov |= (unsigned long long)bit << idx;
            if (fabsf(yv) < 3e-4f) need |= 1ull << idx;
            nib |= (uint32_t)bit << c;
        }
        atomicOr(&pack[rloc][p], nib << shift);
    }
    // rare fp64 recheck of borderline signs; fix bits with atomicXor
    while (need) {
        int idx = __ffsll(need) - 1;
        need &= need - 1ull;
        int p = idx >> 2, c = idx & 3;
        bool nb = recheck_sign(xim, wl, y, p, 4 * cg + c, b0c[c], ivc[c], shc[c]);
        if (nb != (bool)((prov >> idx) & 1ull))
            atomicXor(&pack[rloc][p], 1u << (shift + c));
    }
    __syncthreads();

    for (int i = t; i < 448; i += 256) {
        int rg  = blockIdx.x * 32 + (i / 14);
        int p   = i % 14;
        int im2 = rg / 14, yy = rg - im2 * 14;
        s1bits[im2 * 196 + yy * 14 + p] = ((const uint32_t*)pack)[i];
    }
}

// ============================== convB ==============================
// binary conv2 + BN2 + hardtanh + maxpool + sign -> 36 u32 words per image.
// pooled sign == sign(max(o)*inv2 + sh2) by monotonicity of BN/clip/max.
__global__ __launch_bounds__(256) void convB(
    const uint32_t* __restrict__ s1bits, const uint32_t* __restrict__ w2bits,
    const float* __restrict__ g2, const float* __restrict__ be2,
    const float* __restrict__ m2, const float* __restrict__ v2,
    uint32_t* __restrict__ fcin)
{
    __shared__ uint32_t s1l[4][196];
    __shared__ uint32_t w2l[288];
    __shared__ float iv[32], sh[32];
    const int t = threadIdx.x, wid = t >> 6, lane = t & 63;

    for (int i = t; i < 288; i += 256) w2l[i] = w2bits[i];
    if (t < 32) {
        float v = g2[t] / sqrtf(__fadd_rn(v2[t], EPSF));
        iv[t] = v;
        sh[t] = __fsub_rn(be2[t], __fmul_rn(m2[t], v));
    }
    const int img = blockIdx.x * 4 + wid;
    for (int i = lane; i < 196; i += 64) s1l[wid][i] = s1bits[img * 196 + i];
    __syncthreads();

    uint32_t* outp = fcin + img * 36;
    const uint32_t* s1w = s1l[wid];

    for (int i = 0; i < 18; i++) {
        int k = i * 64 + lane;            // flattened feature 36c + 6y2 + x2
        int c = k / 36, rem = k - c * 36;
        int y2 = rem / 6, x2 = rem - y2 * 6;
        const uint32_t* wc = &w2l[c * 9];
        uint32_t w00 = wc[0], w01 = wc[1], w02 = wc[2],
                 w10 = wc[3], w11 = wc[4], w12 = wc[5],
                 w20 = wc[6], w21 = wc[7], w22 = wc[8];
        int mx = -10000;
        #pragma unroll
        for (int dy = 0; dy < 2; dy++)
            #pragma unroll
            for (int dx = 0; dx < 2; dx++) {
                const uint32_t* rb = &s1w[(2 * y2 + dy) * 14 + 2 * x2 + dx];
                int p = __popc(rb[0]  ^ w00) + __popc(rb[1]  ^ w01) + __popc(rb[2]  ^ w02)
                      + __popc(rb[14] ^ w10) + __popc(rb[15] ^ w11) + __popc(rb[16] ^ w12)
                      + __popc(rb[28] ^ w20) + __popc(rb[29] ^ w21) + __popc(rb[30] ^ w22);
                int o = 288 - 2 * p;
                mx = max(mx, o);
            }
        float yv = __fadd_rn(__fmul_rn((float)mx, iv[c]), sh[c]);
        unsigned long long mb = __ballot(yv < 0.f);
        if (lane == 0)      outp[2 * i]     = (uint32_t)mb;
        else if (lane == 1) outp[2 * i + 1] = (uint32_t)(mb >> 32);
    }
}

// ============================== fcC ==============================
// binary FC (popcount) + BN3 + hardtanh + final 516x10 linear, fused.
// wave handles 4 batches; lane handles features j = lane + 64q, q=0..8 (576 padded).
// fcin words staged through LDS: coalesced fill, then wave-uniform broadcast
// reads (the global path issued 144 per-lane vmcnt-serialized loads/thread).
__global__ __launch_bounds__(256) void fcC(
    const uint32_t* __restrict__ fcin, const uint32_t* __restrict__ wfcb,
    const float* __restrict__ inv3p, const float* __restrict__ sh3p,
    const float* __restrict__ wlt, const float* __restrict__ blast,
    float* __restrict__ out)
{
    __shared__ uint32_t l_in[576];        // 16 batches x 36 words
    const int t = threadIdx.x, wid = t >> 6, lane = t & 63;

    for (int i = t; i < 576; i += 256)
        l_in[i] = fcin[blockIdx.x * 576 + i];
    __syncthreads();

    const int b0i = (blockIdx.x * 4 + wid) * 4;
    const uint32_t* in0 = &l_in[wid * 144];

    float oa[4][10];
    #pragma unroll
    for (int b = 0; b < 4; b++)
        #pragma unroll
        for (int k = 0; k < 10; k++) oa[b][k] = 0.f;

    for (int q = 0; q < 9; q++) {
        int j = lane + 64 * q;
        int p0 = 0, p1 = 0, p2 = 0, p3 = 0;
        const uint32_t* wf = wfcb + j;
        #pragma unroll
        for (int w = 0; w < 36; w++) {
            uint32_t f = wf[w * 576];
            p0 += __popc(in0[w]       ^ f);
            p1 += __popc(in0[36 + w]  ^ f);
            p2 += __popc(in0[72 + w]  ^ f);
            p3 += __popc(in0[108 + w] ^ f);
        }
        float ivv = inv3p[j], shv = sh3p[j];
        float t0 = fminf(1.f, fmaxf(-1.f, __fadd_rn(__fmul_rn((float)(1152 - 2 * p0), ivv), shv)));
        float t1 = fminf(1.f, fmaxf(-1.f, __fadd_rn(__fmul_rn((float)(1152 - 2 * p1), ivv), shv)));
        float t2 = fminf(1.f, fmaxf(-1.f, __fadd_rn(__fmul_rn((float)(1152 - 2 * p2), ivv), shv)));
        float t3 = fminf(1.f, fmaxf(-1.f, __fadd_rn(__fmul_rn((float)(1152 - 2 * p3), ivv), shv)));
        #pragma unroll
        for (int k = 0; k < 10; k++) {
            float wv = wlt[k * 576 + j];  // coalesced across lanes
            oa[0][k] = fmaf(t0, wv, oa[0][k]);
            oa[1][k] = fmaf(t1, wv, oa[1][k]);
            oa[2][k] = fmaf(t2, wv, oa[2][k]);
            oa[3][k] = fmaf(t3, wv, oa[3][k]);
        }
    }

    #pragma unroll
    for (int m = 1; m < 64; m <<= 1)
        #pragma unroll
        for (int b = 0; b < 4; b++)
            #pragma unroll
            for (int k = 0; k < 10; k++)
                oa[b][k] += __shfl_xor(oa[b][k], m, 64);

    if (lane == 0) {
        for (int b = 0; b < 4; b++)
            for (int k = 0; k < 10; k++)
                out[(b0i + b) * 10 + k] = oa[b][k] + blast[k];
    }
}

// ============================== launch ==============================
extern "C" void kernel_launch(void* const* d_in, const int* in_sizes, int n_in,
                              void* d_out, int out_size, void* d_ws, size_t ws_size,
                              hipStream_t stream)
{
    (void)in_sizes; (void)n_in; (void)out_size; (void)ws_size;
    const float* x     = (const float*)d_in[0];
    const float* w0    = (const float*)d_in[1];
    const float* b0    = (const float*)d_in[2];
    const float* g1    = (const float*)d_in[3];
    const float* be1   = (const float*)d_in[4];
    const float* m1    = (const float*)d_in[5];
    const float* v1    = (const float*)d_in[6];
    const float* w2    = (const float*)d_in[7];
    const float* g2    = (const float*)d_in[8];
    const float* be2   = (const float*)d_in[9];
    const float* m2    = (const float*)d_in[10];
    const float* v2    = (const float*)d_in[11];
    const float* wfc   = (const float*)d_in[12];
    const float* g3    = (const float*)d_in[13];
    const float* be3   = (const float*)d_in[14];
    const float* m3    = (const float*)d_in[15];
    const float* v3    = (const float*)d_in[16];
    const float* wlast = (const float*)d_in[17];
    const float* blast = (const float*)d_in[18];

    char* ws = (char*)d_ws;
    uint32_t* s1bits = (uint32_t*)(ws);                 // 8192*196*4 = 6,422,528 B
    uint32_t* fcin   = (uint32_t*)(ws + 6422528);       // 8192*36*4  = 1,179,648 B
    uint32_t* w2bits = (uint32_t*)(ws + 7602176);       // 288*4
    uint32_t* wfcb   = (uint32_t*)(ws + 7603328);       // 36*576*4 = 82,944 B
    float*    inv3p  = (float*)(ws + 7686272);          // 576*4
    float*    sh3p   = (float*)(ws + 7688576);          // 576*4
    float*    wlt    = (float*)(ws + 7690880);          // 10*576*4 = 23,040 B

    prep_kernel<<<107, 256, 0, stream>>>(w2, wfc, g3, be3, m3, v3, wlast,
                                         w2bits, wfcb, inv3p, sh3p, wlt);
    convA<<<3584, 256, 0, stream>>>(x, w0, b0, g1, be1, m1, v1, s1bits);
    convB<<<2048, 256, 0, stream>>>(s1bits, w2bits, g2, be2, m2, v2, fcin);
    fcC<<<512, 256, 0, stream>>>(fcin, wfcb, inv3p, sh3p, wlt, blast, (float*)d_out);
}